// Round 4
// baseline (457.453 us; speedup 1.0000x reference)
//
#include <hip/hip_runtime.h>
#include <math.h>

namespace {

constexpr int B_ = 8;
constexpr int C_ = 256;
constexpr int N_ = 4096;
constexpr int D_ = 8;

constexpr int TM = 64;    // m-rows per attn block
constexpr int TN = 128;   // n-chunk per iteration
constexpr int PSTRIDE = 136;  // ps row stride in bf16 (16B-aligned rows)
constexpr float LOG2E = 1.4426950408889634f;

typedef __attribute__((ext_vector_type(8))) short short8;    // 8 bf16
typedef __attribute__((ext_vector_type(16))) float float16;  // 16 fp32 acc

__device__ inline unsigned short f2bf(float f) {
  unsigned u = __float_as_uint(f);
  u += 0x7FFFu + ((u >> 16) & 1u);   // RNE
  return (unsigned short)(u >> 16);
}
__device__ inline float bf2f(unsigned short h) {
  return __uint_as_float(((unsigned)h) << 16);
}

// ---- wv -> bf16 ----
__global__ __launch_bounds__(256) void prep_kernel(
    const float* __restrict__ wv, unsigned short* __restrict__ wv_bf) {
  const int i = blockIdx.x * 1024 + threadIdx.x;
  #pragma unroll
  for (int j = 0; j < 4; ++j) wv_bf[i + 256 * j] = f2bf(wv[i + 256 * j]);
}

// ---- fused projection: one pass over x ----
// Stage x tile (64n x 256c) as bf16 in LDS; while staging, accumulate q/k
// scalar fp32 partials (this lane's 64-c range); LDS-reduce q/k across the
// 4 waves and emit hi/lo split layouts; then V = Wv(bf16) . X(bf16) via MFMA.
__global__ __launch_bounds__(256, 3) void proj_kernel(
    const float* __restrict__ x,
    const float* __restrict__ wq, const float* __restrict__ bq,
    const float* __restrict__ wk, const float* __restrict__ bk,
    const unsigned short* __restrict__ wv_bf, const float* __restrict__ bv,
    unsigned short* __restrict__ q_t, unsigned short* __restrict__ k_th,
    unsigned short* __restrict__ k_tl, unsigned short* __restrict__ v)
{
  __shared__ __align__(16) unsigned short xs[64][264];  // [n][c], 528B row (16B mult)
  __shared__ float red[4][16][64];                      // q/k partials per wave

  const int b = blockIdx.y;
  const int n0 = blockIdx.x * 64;
  const int tid = threadIdx.x;
  const int w = tid >> 6, l = tid & 63;
  const int l31 = l & 31, lh = l >> 5;

  float a[16];
  #pragma unroll
  for (int d = 0; d < 16; ++d) a[d] = 0.f;

  // lane: n = n0 + l, c-range [64w, 64w+64)
  const float* xb = x + ((size_t)b * C_ + w * 64) * N_ + n0 + l;
  #pragma unroll 4
  for (int i = 0; i < 64; i += 4) {
    float xv[4];
    #pragma unroll
    for (int j = 0; j < 4; ++j) xv[j] = xb[(size_t)(i + j) * N_];
    ushort4 pk;
    pk.x = f2bf(xv[0]); pk.y = f2bf(xv[1]); pk.z = f2bf(xv[2]); pk.w = f2bf(xv[3]);
    *reinterpret_cast<ushort4*>(&xs[l][w * 64 + i]) = pk;
    #pragma unroll
    for (int j = 0; j < 4; ++j) {
      const int c = w * 64 + i + j;
      #pragma unroll
      for (int d = 0; d < 8; ++d) {
        a[d]     = fmaf(wq[d * C_ + c], xv[j], a[d]);
        a[8 + d] = fmaf(wk[d * C_ + c], xv[j], a[8 + d]);
      }
    }
  }
  #pragma unroll
  for (int d = 0; d < 16; ++d) red[w][d][l] = a[d];
  __syncthreads();

  // q/k finalize: idx -> (d, n)
  #pragma unroll
  for (int p = 0; p < 4; ++p) {
    const int idx = tid + 256 * p;
    const int d = idx >> 6, n = idx & 63;
    const float vv = red[0][d][n] + red[1][d][n] + red[2][d][n] + red[3][d][n];
    const size_t gn = (size_t)b * N_ + n0 + n;
    if (d < 8) {
      const float qs = (vv + bq[d]) * LOG2E;
      const unsigned short hi = f2bf(qs);
      const unsigned short lo = f2bf(qs - bf2f(hi));
      q_t[gn * 16 + d] = hi;
      q_t[gn * 16 + 8 + d] = lo;
    } else {
      const float ks = vv + bk[d - 8];
      const unsigned short hi = f2bf(ks);
      const unsigned short lo = f2bf(ks - bf2f(hi));
      k_th[gn * 8 + d - 8] = hi;
      k_tl[gn * 8 + d - 8] = lo;
    }
  }

  // V: wave w -> c_out [64w, 64w+64) x n [0,64): 2x2 accs of 32x32
  float16 acc[2][2];
  #pragma unroll
  for (int mi = 0; mi < 2; ++mi)
    #pragma unroll
    for (int ni = 0; ni < 2; ++ni)
      #pragma unroll
      for (int r = 0; r < 16; ++r) acc[mi][ni][r] = 0.f;

  for (int ks = 0; ks < 16; ++ks) {
    short8 af[2], bfg[2];
    #pragma unroll
    for (int mi = 0; mi < 2; ++mi)
      af[mi] = *reinterpret_cast<const short8*>(
          wv_bf + (w * 64 + mi * 32 + l31) * C_ + ks * 16 + lh * 8);
    #pragma unroll
    for (int ni = 0; ni < 2; ++ni)
      bfg[ni] = *reinterpret_cast<const short8*>(&xs[ni * 32 + l31][ks * 16 + lh * 8]);
    #pragma unroll
    for (int mi = 0; mi < 2; ++mi)
      #pragma unroll
      for (int ni = 0; ni < 2; ++ni)
        acc[mi][ni] = __builtin_amdgcn_mfma_f32_32x32x16_bf16(af[mi], bfg[ni], acc[mi][ni], 0, 0, 0);
  }

  #pragma unroll
  for (int mi = 0; mi < 2; ++mi)
    #pragma unroll
    for (int r = 0; r < 16; ++r) {
      const int c = w * 64 + mi * 32 + (r & 3) + 8 * (r >> 2) + 4 * lh;
      const float bvc = bv[c];
      #pragma unroll
      for (int ni = 0; ni < 2; ++ni) {
        const int n = n0 + ni * 32 + l31;
        v[((size_t)b * C_ + c) * N_ + n] = f2bf(acc[mi][ni][r] + bvc);
      }
    }
}

// ---- fused attention: QK-MFMA (hi/lo exact) -> exp -> PV-MFMA ----
__global__ __launch_bounds__(512, 6) void attn_kernel(
    const unsigned short* __restrict__ q_t, const unsigned short* __restrict__ k_th,
    const unsigned short* __restrict__ k_tl, const unsigned short* __restrict__ v,
    const float* __restrict__ x, const float* __restrict__ gamma,
    float* __restrict__ out)
{
  __shared__ __align__(16) unsigned short ps[2][TM][PSTRIDE];
  __shared__ float rsp[4][TM];
  __shared__ float rsn[TM];

  const int b = blockIdx.x;           // batch -> XCD affinity
  const int m0 = blockIdx.y * TM;
  const int tid = threadIdx.x;
  const int w = tid >> 6;
  const int l = tid & 63;
  const int l31 = l & 31, lh = l >> 5;
  const int mt = w >> 2, nt = w & 3;  // QK score tile of this wave

  const short8 aq = *reinterpret_cast<const short8*>(
      q_t + ((size_t)b * N_ + m0 + 32 * mt + l31) * 16 + lh * 8);

  const unsigned short* vrow = v + ((size_t)b * C_ + w * 32 + l31) * N_;
  const unsigned short* kbh = k_th + (size_t)b * N_ * 8;
  const unsigned short* kbl = k_tl + (size_t)b * N_ * 8;

  float16 o0, o1;
  float rsum[16];
  #pragma unroll
  for (int r = 0; r < 16; ++r) { o0[r] = 0.f; o1[r] = 0.f; rsum[r] = 0.f; }

  for (int nc = 0; nc < N_ / TN; ++nc) {
    const int n0 = nc * TN;
    const int buf = nc & 1;

    // prefetch first half of this chunk's V A-frags (latency hidden by
    // QK + exp + barrier; second half loaded under the first 8 PV MFMAs)
    short8 af0[4];
    #pragma unroll
    for (int g = 0; g < 4; ++g)
      af0[g] = *reinterpret_cast<const short8*>(vrow + n0 + g * 16 + lh * 8);

    // --- QK: s = (qh+ql).(kh+kl) via two chained MFMAs (log2 domain) ---
    const int nq = n0 + nt * 32 + l31;
    const short8 bh = *reinterpret_cast<const short8*>(kbh + (size_t)nq * 8);
    const short8 bl = *reinterpret_cast<const short8*>(kbl + (size_t)nq * 8);
    float16 s;
    #pragma unroll
    for (int r = 0; r < 16; ++r) s[r] = 0.f;
    s = __builtin_amdgcn_mfma_f32_32x32x16_bf16(aq, bh, s, 0, 0, 0);
    s = __builtin_amdgcn_mfma_f32_32x32x16_bf16(aq, bl, s, 0, 0, 0);

    // --- exp (base-2, q pre-scaled) + bf16 P into LDS ---
    #pragma unroll
    for (int r = 0; r < 16; ++r) {
      const float e = exp2f(s[r]);
      rsum[r] += e;
      const int mrow = 32 * mt + (r & 3) + 8 * (r >> 2) + 4 * lh;
      ps[buf][mrow][nt * 32 + l31] = f2bf(e);
    }
    __syncthreads();

    // --- PV: D[c][m] += V[c][n] . P^T ---
    #pragma unroll
    for (int ks = 0; ks < 8; ++ks) {
      const short8 a = (ks < 4)
          ? af0[ks & 3]
          : *reinterpret_cast<const short8*>(vrow + n0 + ks * 16 + lh * 8);
      const short8 p0 = *reinterpret_cast<const short8*>(&ps[buf][l31][ks * 16 + lh * 8]);
      const short8 p1 = *reinterpret_cast<const short8*>(&ps[buf][32 + l31][ks * 16 + lh * 8]);
      o0 = __builtin_amdgcn_mfma_f32_32x32x16_bf16(a, p0, o0, 0, 0, 0);
      o1 = __builtin_amdgcn_mfma_f32_32x32x16_bf16(a, p1, o1, 0, 0, 0);
    }
  }

  // --- row sums: reduce over the 32 n-lanes, stash per nt-wave, combine ---
  #pragma unroll
  for (int r = 0; r < 16; ++r) {
    float ss = rsum[r];
    #pragma unroll
    for (int off = 16; off >= 1; off >>= 1) ss += __shfl_xor(ss, off);
    rsum[r] = ss;
  }
  if (l31 == 0) {
    #pragma unroll
    for (int r = 0; r < 16; ++r) {
      const int mrow = 32 * mt + (r & 3) + 8 * (r >> 2) + 4 * lh;
      rsp[nt][mrow] = rsum[r];
    }
  }
  __syncthreads();
  if (tid < TM) rsn[tid] = rsp[0][tid] + rsp[1][tid] + rsp[2][tid] + rsp[3][tid];
  __syncthreads();

  // --- epilogue: out = gamma/rowsum * O + x ---
  const float g = gamma[0];
  const float t0 = g / rsn[l31];
  const float t1 = g / rsn[32 + l31];
  #pragma unroll
  for (int r = 0; r < 16; ++r) {
    const int c = 32 * w + (r & 3) + 8 * (r >> 2) + 4 * lh;
    const size_t i0 = ((size_t)b * C_ + c) * N_ + m0 + l31;
    out[i0]      = fmaf(o0[r], t0, x[i0]);
    out[i0 + 32] = fmaf(o1[r], t1, x[i0 + 32]);
  }
}

}  // namespace

extern "C" void kernel_launch(void* const* d_in, const int* in_sizes, int n_in,
                              void* d_out, int out_size, void* d_ws, size_t ws_size,
                              hipStream_t stream) {
  const float* x     = (const float*)d_in[0];
  const float* wq    = (const float*)d_in[1];
  const float* bq    = (const float*)d_in[2];
  const float* wk    = (const float*)d_in[3];
  const float* bk    = (const float*)d_in[4];
  const float* wv    = (const float*)d_in[5];
  const float* bv    = (const float*)d_in[6];
  const float* gamma = (const float*)d_in[7];
  float* out = (float*)d_out;

  // ws: q_t 1MB | k_th 0.5MB | k_tl 0.5MB | wv_bf 128KB | v 16MB
  char* p = (char*)d_ws;
  unsigned short* q_t   = (unsigned short*)p;                 p += (size_t)B_ * N_ * 16 * 2;
  unsigned short* k_th  = (unsigned short*)p;                 p += (size_t)B_ * N_ * 8 * 2;
  unsigned short* k_tl  = (unsigned short*)p;                 p += (size_t)B_ * N_ * 8 * 2;
  unsigned short* wv_bf = (unsigned short*)p;                 p += (size_t)C_ * C_ * 2;
  unsigned short* v     = (unsigned short*)p;

  prep_kernel<<<dim3(C_ * C_ / 1024), 256, 0, stream>>>(wv, wv_bf);
  proj_kernel<<<dim3(N_ / 64, B_), 256, 0, stream>>>(x, wq, bq, wk, bk, wv_bf, bv,
                                                     q_t, k_th, k_tl, v);
  attn_kernel<<<dim3(B_, N_ / TM), 512, 0, stream>>>(q_t, k_th, k_tl, v, x, gamma, out);
}

// Round 5
// 241.307 us; speedup vs baseline: 1.8957x; 1.8957x over previous
//
#include <hip/hip_runtime.h>
#include <math.h>

namespace {

constexpr int B_ = 8;
constexpr int C_ = 256;
constexpr int N_ = 4096;

constexpr int TM = 64;    // m-rows per attn block
constexpr int TN = 128;   // n-chunk per iteration
constexpr int PSTRIDE = 136;  // ps row stride in bf16 (16B-aligned rows)
constexpr float LOG2E = 1.4426950408889634f;

typedef __attribute__((ext_vector_type(8))) short short8;    // 8 bf16
typedef __attribute__((ext_vector_type(16))) float float16;  // 16 fp32 acc

__device__ inline unsigned short f2bf(float f) {
  unsigned u = __float_as_uint(f);
  u += 0x7FFFu + ((u >> 16) & 1u);   // RNE
  return (unsigned short)(u >> 16);
}
__device__ inline float bf2f(unsigned short h) {
  return __uint_as_float(((unsigned)h) << 16);
}

// ---- prep: wv -> bf16 ; wqk A-matrix [wq*log2e hi(8); lo(8); wk hi(8); lo(8)] ----
__global__ __launch_bounds__(256) void prep_kernel(
    const float* __restrict__ wv, const float* __restrict__ wq,
    const float* __restrict__ wk,
    unsigned short* __restrict__ wv_bf, unsigned short* __restrict__ wqk_bf) {
  const int i = blockIdx.x * 256 + threadIdx.x;   // grid 256 -> 65536 threads
  wv_bf[i] = f2bf(wv[i]);
  if (i < 2048) {
    const int d = i >> 8, c = i & 255;
    const float qL = wq[i] * LOG2E;
    const unsigned short hq = f2bf(qL);
    wqk_bf[d * 256 + c]        = hq;
    wqk_bf[(d + 8) * 256 + c]  = f2bf(qL - bf2f(hq));
    const float kv = wk[i];
    const unsigned short hk = f2bf(kv);
    wqk_bf[(d + 16) * 256 + c] = hk;
    wqk_bf[(d + 24) * 256 + c] = f2bf(kv - bf2f(hk));
  }
}

// Build a bf16 B-fragment (8 consecutive k=c values at column n) from fp32 LDS.
__device__ inline short8 xfrag(const float* xs, int c0, int n) {
  short8 r;
  #pragma unroll
  for (int i = 0; i < 8; ++i) r[i] = (short)f2bf(xs[(c0 + i) * 64 + n]);
  return r;
}

// ---- fused projection, all-MFMA, async-staged ----
// Stage x tile (256c x 64n) fp32 into LDS via global_load_lds (wave-uniform LDS
// base + lane*4 = one 256B c-row per instr, 64 async per wave). Then:
//  waves 0,1: q/k = wqk_bf(32x256) . X  (hi/lo weights -> near-fp32 exact)
//  all waves: V = wv_bf(256x256) . X, bf16 out.
__global__ __launch_bounds__(256, 2) void proj_kernel(
    const float* __restrict__ x,
    const float* __restrict__ bq, const float* __restrict__ bk,
    const unsigned short* __restrict__ wqk_bf,
    const unsigned short* __restrict__ wv_bf, const float* __restrict__ bv,
    unsigned short* __restrict__ q_t, unsigned short* __restrict__ k_th,
    unsigned short* __restrict__ k_tl, unsigned short* __restrict__ v)
{
  __shared__ float xs[256 * 64];   // [c][n] fp32, 64 KB -> 2 blocks/CU

  const int b = blockIdx.y;
  const int n0 = blockIdx.x * 64;
  const int tid = threadIdx.x;
  const int w = tid >> 6, l = tid & 63;
  const int l31 = l & 31, lh = l >> 5;

  // async stage: wave w covers c rows [64w, 64w+64)
  {
    const float* gp = x + ((size_t)b * C_ + w * 64) * N_ + n0 + l;  // per-lane
    const float* lp = xs + (w * 64) * 64;                           // wave-uniform
    #pragma unroll
    for (int i = 0; i < 64; ++i) {
      __builtin_amdgcn_global_load_lds(
          (const __attribute__((address_space(1))) void*)(gp + (size_t)i * N_),
          (__attribute__((address_space(3))) void*)(lp + i * 64), 4, 0, 0);
    }
  }
  __syncthreads();   // drains vmcnt before barrier

  // q/k MFMA: waves 0,1 -> D[32 d-rows][32 n], n-tile = [32w, 32w+32)
  float16 sacc;
  if (w < 2) {
    #pragma unroll
    for (int r = 0; r < 16; ++r) sacc[r] = 0.f;
    for (int ks = 0; ks < 16; ++ks) {
      const short8 a = *reinterpret_cast<const short8*>(
          wqk_bf + l31 * 256 + ks * 16 + lh * 8);
      const short8 bfg = xfrag(xs, ks * 16 + lh * 8, w * 32 + l31);
      sacc = __builtin_amdgcn_mfma_f32_32x32x16_bf16(a, bfg, sacc, 0, 0, 0);
    }
    // rows: d=q_hi, d+8=q_lo, d+16=k_hi, d+24=k_lo ; lane holds d = r+4*lh, r<4
    const size_t gn = (size_t)b * N_ + n0 + w * 32 + l31;
    #pragma unroll
    for (int r = 0; r < 4; ++r) {
      const int d = r + 4 * lh;
      const float qv = sacc[r] + sacc[r + 4] + bq[d] * LOG2E;
      const unsigned short hq = f2bf(qv);
      q_t[gn * 16 + d]     = hq;
      q_t[gn * 16 + 8 + d] = f2bf(qv - bf2f(hq));
      const float kv = sacc[r + 8] + sacc[r + 12] + bk[d];
      const unsigned short hk = f2bf(kv);
      k_th[gn * 8 + d] = hk;
      k_tl[gn * 8 + d] = f2bf(kv - bf2f(hk));
    }
  }

  // V: wave w -> c_out [64w, 64w+64) x n [0,64): 2x2 accs of 32x32
  float16 acc[2][2];
  #pragma unroll
  for (int mi = 0; mi < 2; ++mi)
    #pragma unroll
    for (int ni = 0; ni < 2; ++ni)
      #pragma unroll
      for (int r = 0; r < 16; ++r) acc[mi][ni][r] = 0.f;

  for (int ks = 0; ks < 16; ++ks) {
    short8 af[2], bfg[2];
    #pragma unroll
    for (int mi = 0; mi < 2; ++mi)
      af[mi] = *reinterpret_cast<const short8*>(
          wv_bf + (w * 64 + mi * 32 + l31) * C_ + ks * 16 + lh * 8);
    #pragma unroll
    for (int ni = 0; ni < 2; ++ni)
      bfg[ni] = xfrag(xs, ks * 16 + lh * 8, ni * 32 + l31);
    #pragma unroll
    for (int mi = 0; mi < 2; ++mi)
      #pragma unroll
      for (int ni = 0; ni < 2; ++ni)
        acc[mi][ni] = __builtin_amdgcn_mfma_f32_32x32x16_bf16(af[mi], bfg[ni], acc[mi][ni], 0, 0, 0);
  }

  #pragma unroll
  for (int mi = 0; mi < 2; ++mi)
    #pragma unroll
    for (int r = 0; r < 16; ++r) {
      const int c = w * 64 + mi * 32 + (r & 3) + 8 * (r >> 2) + 4 * lh;
      const float bvc = bv[c];
      #pragma unroll
      for (int ni = 0; ni < 2; ++ni) {
        const int n = n0 + ni * 32 + l31;
        v[((size_t)b * C_ + c) * N_ + n] = f2bf(acc[mi][ni][r] + bvc);
      }
    }
}

// ---- fused attention: QK-MFMA (hi/lo exact) -> exp -> PV-MFMA ----
// launch_bounds (512,4): 2 blocks/CU, 128-reg budget — (512,6) spills (R4 post-mortem).
__global__ __launch_bounds__(512, 4) void attn_kernel(
    const unsigned short* __restrict__ q_t, const unsigned short* __restrict__ k_th,
    const unsigned short* __restrict__ k_tl, const unsigned short* __restrict__ v,
    const float* __restrict__ x, const float* __restrict__ gamma,
    float* __restrict__ out)
{
  __shared__ __align__(16) unsigned short ps[2][TM][PSTRIDE];
  __shared__ float rsp[4][TM];
  __shared__ float rsn[TM];

  const int b = blockIdx.x;           // batch -> XCD affinity
  const int m0 = blockIdx.y * TM;
  const int tid = threadIdx.x;
  const int w = tid >> 6;
  const int l = tid & 63;
  const int l31 = l & 31, lh = l >> 5;
  const int mt = w >> 2, nt = w & 3;  // QK score tile of this wave

  const short8 aq = *reinterpret_cast<const short8*>(
      q_t + ((size_t)b * N_ + m0 + 32 * mt + l31) * 16 + lh * 8);

  const unsigned short* vrow = v + ((size_t)b * C_ + w * 32 + l31) * N_;
  const unsigned short* kbh = k_th + (size_t)b * N_ * 8;
  const unsigned short* kbl = k_tl + (size_t)b * N_ * 8;

  float16 o0, o1;
  float rsum[16];
  #pragma unroll
  for (int r = 0; r < 16; ++r) { o0[r] = 0.f; o1[r] = 0.f; rsum[r] = 0.f; }

  // prime chunk-0 k fragments
  short8 bh = *reinterpret_cast<const short8*>(kbh + (size_t)(nt * 32 + l31) * 8);
  short8 bl = *reinterpret_cast<const short8*>(kbl + (size_t)(nt * 32 + l31) * 8);

  for (int nc = 0; nc < N_ / TN; ++nc) {
    const int n0 = nc * TN;
    const int buf = nc & 1;

    // prefetch all 8 V A-frags for THIS chunk (latency hides under QK+exp+barrier)
    short8 af[8];
    #pragma unroll
    for (int g = 0; g < 8; ++g)
      af[g] = *reinterpret_cast<const short8*>(vrow + n0 + g * 16 + lh * 8);

    // prefetch NEXT chunk's k frags (consumed next iteration)
    const int n1 = ((nc + 1) & (N_ / TN - 1)) * TN + nt * 32 + l31;
    const short8 bh2 = *reinterpret_cast<const short8*>(kbh + (size_t)n1 * 8);
    const short8 bl2 = *reinterpret_cast<const short8*>(kbl + (size_t)n1 * 8);

    // --- QK: s = (qh+ql).(kh+kl) via two chained MFMAs (log2 domain) ---
    float16 s;
    #pragma unroll
    for (int r = 0; r < 16; ++r) s[r] = 0.f;
    s = __builtin_amdgcn_mfma_f32_32x32x16_bf16(aq, bh, s, 0, 0, 0);
    s = __builtin_amdgcn_mfma_f32_32x32x16_bf16(aq, bl, s, 0, 0, 0);

    // --- exp (base-2, q pre-scaled) + bf16 P into LDS ---
    #pragma unroll
    for (int r = 0; r < 16; ++r) {
      const float e = exp2f(s[r]);
      rsum[r] += e;
      const int mrow = 32 * mt + (r & 3) + 8 * (r >> 2) + 4 * lh;
      ps[buf][mrow][nt * 32 + l31] = f2bf(e);
    }
    __syncthreads();

    // --- PV: D[c][m] += V[c][n] . P^T ---
    #pragma unroll
    for (int ks = 0; ks < 8; ++ks) {
      const short8 p0 = *reinterpret_cast<const short8*>(&ps[buf][l31][ks * 16 + lh * 8]);
      const short8 p1 = *reinterpret_cast<const short8*>(&ps[buf][32 + l31][ks * 16 + lh * 8]);
      o0 = __builtin_amdgcn_mfma_f32_32x32x16_bf16(af[ks], p0, o0, 0, 0, 0);
      o1 = __builtin_amdgcn_mfma_f32_32x32x16_bf16(af[ks], p1, o1, 0, 0, 0);
    }
    bh = bh2; bl = bl2;
  }

  // --- row sums: reduce over the 32 n-lanes, stash per nt-wave, combine ---
  #pragma unroll
  for (int r = 0; r < 16; ++r) {
    float ss = rsum[r];
    #pragma unroll
    for (int off = 16; off >= 1; off >>= 1) ss += __shfl_xor(ss, off);
    rsum[r] = ss;
  }
  if (l31 == 0) {
    #pragma unroll
    for (int r = 0; r < 16; ++r) {
      const int mrow = 32 * mt + (r & 3) + 8 * (r >> 2) + 4 * lh;
      rsp[nt][mrow] = rsum[r];
    }
  }
  __syncthreads();
  if (tid < TM) rsn[tid] = rsp[0][tid] + rsp[1][tid] + rsp[2][tid] + rsp[3][tid];
  __syncthreads();

  // --- epilogue: out = gamma/rowsum * O + x ---
  const float g = gamma[0];
  const float t0 = g / rsn[l31];
  const float t1 = g / rsn[32 + l31];
  #pragma unroll
  for (int r = 0; r < 16; ++r) {
    const int c = 32 * w + (r & 3) + 8 * (r >> 2) + 4 * lh;
    const size_t i0 = ((size_t)b * C_ + c) * N_ + m0 + l31;
    out[i0]      = fmaf(o0[r], t0, x[i0]);
    out[i0 + 32] = fmaf(o1[r], t1, x[i0 + 32]);
  }
}

}  // namespace

extern "C" void kernel_launch(void* const* d_in, const int* in_sizes, int n_in,
                              void* d_out, int out_size, void* d_ws, size_t ws_size,
                              hipStream_t stream) {
  const float* x     = (const float*)d_in[0];
  const float* wq    = (const float*)d_in[1];
  const float* bq    = (const float*)d_in[2];
  const float* wk    = (const float*)d_in[3];
  const float* bk    = (const float*)d_in[4];
  const float* wv    = (const float*)d_in[5];
  const float* bv    = (const float*)d_in[6];
  const float* gamma = (const float*)d_in[7];
  float* out = (float*)d_out;

  // ws: q_t 1MB | k_th .5MB | k_tl .5MB | wv_bf 128KB | wqk_bf 16KB | v 16MB
  char* p = (char*)d_ws;
  unsigned short* q_t    = (unsigned short*)p;  p += (size_t)B_ * N_ * 16 * 2;
  unsigned short* k_th   = (unsigned short*)p;  p += (size_t)B_ * N_ * 8 * 2;
  unsigned short* k_tl   = (unsigned short*)p;  p += (size_t)B_ * N_ * 8 * 2;
  unsigned short* wv_bf  = (unsigned short*)p;  p += (size_t)C_ * C_ * 2;
  unsigned short* wqk_bf = (unsigned short*)p;  p += (size_t)32 * C_ * 2;
  unsigned short* v      = (unsigned short*)p;

  prep_kernel<<<dim3(C_ * C_ / 256), 256, 0, stream>>>(wv, wq, wk, wv_bf, wqk_bf);
  proj_kernel<<<dim3(N_ / 64, B_), 256, 0, stream>>>(x, bq, bk, wqk_bf, wv_bf, bv,
                                                     q_t, k_th, k_tl, v);
  attn_kernel<<<dim3(B_, N_ / TM), 512, 0, stream>>>(q_t, k_th, k_tl, v, x, gamma, out);
}